// Round 17
// baseline (978.760 us; speedup 1.0000x reference)
//
#include <hip/hip_runtime.h>
#include <hip/hip_bf16.h>

#define NWORDS 8192
#define LW 24
#define DIM 256
#define NHEAD 8
#define DFF 1024
#define NCONC 1024
#define MAXW 16
#define TN (NCONC * MAXW)          // 16384 name tokens

typedef float floatx4 __attribute__((ext_vector_type(4)));
typedef short shortx8 __attribute__((ext_vector_type(8)));

__device__ __forceinline__ float bf2f(ushort u) {
  union { uint u; float f; } v; v.u = ((uint)u) << 16; return v.f;
}
__device__ __forceinline__ ushort f2bf(float f) {
  union { float f; uint u; } v; v.f = f;
  return (ushort)((v.u + 0x7FFFu + ((v.u >> 16) & 1u)) >> 16);
}

// async global->LDS, 16B per lane; LDS dst is wave-uniform base + lane*16
__device__ __forceinline__ void load_lds16(const ushort* gsrc, ushort* lds) {
  __builtin_amdgcn_global_load_lds((const __attribute__((address_space(1))) void*)gsrc,
                                   (__attribute__((address_space(3))) void*)lds, 16, 0, 0);
}

// s_waitcnt imm: vmcnt[3:0]=b3:0,[5:4]=b15:14; expcnt=b6:4; lgkmcnt=b11:8
#define WAIT_VM0() __builtin_amdgcn_s_waitcnt(0x0F70)    // vmcnt(0), others max
#define WAIT_LGKM0() __builtin_amdgcn_s_waitcnt(0xC07F)  // lgkmcnt(0), others max

// Swizzled LDS tile (R6-verified: SQ_LDS_BANK_CONFLICT == 0): rows of 32 ushort
// (64B) in 4 16B chunks; chunk c of row r stored at slot c ^ ((r>>1)&3).
#define STAGE_COL(lane) ((((lane) & 3) ^ (((lane) >> 3) & 3)) * 8)
#define FRAG_OFF(row, quad) (((row) * 32) + ((((quad) ^ (((row) >> 1) & 3))) * 8))

// ---------------- weight transpose + cast: W[K x N] f32 -> WT[N x K] bf16
__global__ __launch_bounds__(256) void wprep(const float* __restrict__ W,
                                             ushort* __restrict__ WT, int K, int N) {
  int idx = blockIdx.x * 256 + threadIdx.x;
  if (idx < K * N) {
    int k = idx / N, n = idx % N;
    WT[n * K + k] = f2bf(W[idx]);
  }
}

// ---------------- embedding gather -> bf16 x (vectorized: 1 thread = 4 elems)
__global__ __launch_bounds__(256) void embed4(const int* __restrict__ inputs,
                                              const float* __restrict__ we_emb,
                                              ushort* __restrict__ x, int ntok) {
  int idx = blockIdx.x * 256 + threadIdx.x;
  int t = idx >> 6, d = (idx & 63) * 4;
  if (t < ntok) {
    const float4 f = *(const float4*)&we_emb[inputs[t] * DIM + d];
    uint2 o;
    o.x = (uint)f2bf(f.x) | ((uint)f2bf(f.y) << 16);
    o.y = (uint)f2bf(f.z) | ((uint)f2bf(f.w) << 16);
    *(uint2*)&x[(size_t)t * DIM + d] = o;
  }
}

// ---------------- GEMM, K=256 fixed, 64 tokens/block; NTILES N-tiles of 256
// processed in-block (A-tile staged ONCE, reused across tiles — QKV no longer
// re-stages A 3x).  Weights per-wave staged with s_waitcnt fences ->
// barrier-free K-loop.  Optional residual+LN (requires NTILES==1).
template <bool LN, int NTILES>
__global__ __launch_bounds__(256, 2) void gemm_tok64(const ushort* __restrict__ A, int lda,
                                                     const ushort* __restrict__ BT,  // [N x 256]
                                                     const ushort* __restrict__ RES, // [M x 256] | null
                                                     ushort* __restrict__ C, int ldc) {
  __shared__ __align__(16) ushort As[8 * 64 * 32];  // tokens: 8 k-planes x 64 rows (32 KB)
  __shared__ __align__(16) ushort Wb[256 * 32];     // weight plane; wave w owns rows w*64.. (16 KB)
  __shared__ float red1[64 * 4];
  __shared__ float red2[64 * 4];
  const int tid = threadIdx.x;
  const int w = tid >> 6, lane = tid & 63;
  const int quad = lane >> 4, l16 = lane & 15;
  const long m0 = (long)blockIdx.y * 64;
  const int srow = lane >> 2;
  const int scol = STAGE_COL(lane);
  const int wc = w * 64;

  // stage A tile once: 8 planes x 4 row-groups = 32 insts, 8 per wave
#pragma unroll
  for (int t = 0; t < 8; t++) {
    int p = 2 * w + t / 4, ii = t % 4;
    load_lds16(&A[(m0 + ii * 16 + srow) * lda + p * 32 + scol], &As[p * 2048 + (ii * 16) * 32]);
  }
  // prestage weight plane 0 of tile 0 (wave's own quarter)
#pragma unroll
  for (int ii = 0; ii < 4; ii++)
    load_lds16(&BT[(wc + ii * 16 + srow) * 256 + scol], &Wb[(wc + ii * 16) * 32]);
  __syncthreads();   // As (cross-wave) + own Wb plane 0 ready

#pragma unroll 1
  for (int nt = 0; nt < NTILES; nt++) {
    const long nb = (long)nt * 256;
    floatx4 acc[4][4] = {};
#pragma unroll 1
    for (int p = 0; p < 8; p++) {        // K plane — per-wave fences, no barriers
      WAIT_VM0();                        // own staged plane landed
      shortx8 a[4], b[4];
#pragma unroll
      for (int j = 0; j < 4; j++)
        b[j] = *(const shortx8*)&Wb[FRAG_OFF(wc + j * 16 + l16, quad)];
      WAIT_LGKM0();                      // frags in VGPRs; Wb quarter reusable
      // stage next plane: p+1 of this tile, or plane 0 of the next tile
      if (p < 7) {
#pragma unroll
        for (int ii = 0; ii < 4; ii++)
          load_lds16(&BT[(nb + wc + ii * 16 + srow) * 256 + (p + 1) * 32 + scol],
                     &Wb[(wc + ii * 16) * 32]);
      } else if (nt + 1 < NTILES) {
#pragma unroll
        for (int ii = 0; ii < 4; ii++)
          load_lds16(&BT[(nb + 256 + wc + ii * 16 + srow) * 256 + scol],
                     &Wb[(wc + ii * 16) * 32]);
      }
#pragma unroll
      for (int i = 0; i < 4; i++)
        a[i] = *(const shortx8*)&As[p * 2048 + FRAG_OFF(i * 16 + l16, quad)];
#pragma unroll
      for (int i = 0; i < 4; i++)
#pragma unroll
        for (int j = 0; j < 4; j++)
          acc[i][j] = __builtin_amdgcn_mfma_f32_16x16x32_bf16(a[i], b[j], acc[i][j], 0, 0, 0);
    }

    if (!LN) {
      // plain store (used for QKV; C is the 768-wide qkv buffer)
#pragma unroll
      for (int i = 0; i < 4; i++)
#pragma unroll
        for (int j = 0; j < 4; j++)
#pragma unroll
          for (int r = 0; r < 4; r++) {
            long m = m0 + i * 16 + quad * 4 + r;
            C[m * ldc + nb + wc + j * 16 + l16] = f2bf(acc[i][j][r]);
          }
    } else {
      // residual + LN epilogue (N==256, NTILES==1 -> nb==0)
#pragma unroll
      for (int i = 0; i < 4; i++)
#pragma unroll
        for (int r = 0; r < 4; r++) {
          int row = i * 16 + quad * 4 + r;
          float s1 = 0.f, s2 = 0.f;
#pragma unroll
          for (int j = 0; j < 4; j++) {
            float v = acc[i][j][r] + bf2f(RES[(m0 + row) * 256 + wc + j * 16 + l16]);
            acc[i][j][r] = v;
            s1 += v;
            s2 += v * v;
          }
#pragma unroll
          for (int off = 1; off < 16; off <<= 1) {
            s1 += __shfl_xor(s1, off);
            s2 += __shfl_xor(s2, off);
          }
          if (l16 == 0) { red1[row * 4 + w] = s1; red2[row * 4 + w] = s2; }
        }
      __syncthreads();
#pragma unroll
      for (int i = 0; i < 4; i++)
#pragma unroll
        for (int r = 0; r < 4; r++) {
          int row = i * 16 + quad * 4 + r;
          float s1 = red1[row * 4] + red1[row * 4 + 1] + red1[row * 4 + 2] + red1[row * 4 + 3];
          float s2 = red2[row * 4] + red2[row * 4 + 1] + red2[row * 4 + 2] + red2[row * 4 + 3];
          float mean = s1 * (1.f / 256.f);
          float rstd = rsqrtf(s2 * (1.f / 256.f) - mean * mean + 1e-5f);
#pragma unroll
          for (int j = 0; j < 4; j++)
            C[(m0 + row) * 256 + wc + j * 16 + l16] = f2bf((acc[i][j][r] - mean) * rstd);
        }
    }
  }
}

// ---------------- fused FFN: C = LN(h + relu(h W1) W2), 64 rows/block, 4 waves.
// (R12/R14 winner, unchanged)
__global__ __launch_bounds__(256, 2) void ffn_fused(const ushort* __restrict__ H,   // [M x 256]
                                                    const ushort* __restrict__ W1T, // [1024 x 256]
                                                    const ushort* __restrict__ W2T, // [256 x 1024]
                                                    ushort* __restrict__ C,         // [M x 256]
                                                    int M) {
  __shared__ __align__(16) ushort As[8 * 64 * 32];  // h: 8 k-planes x 64 rows (32 KB)
  __shared__ __align__(16) ushort Ss[8 * 64 * 32];  // S macro: 8 planes x 64 rows (32 KB)
  __shared__ __align__(16) ushort Wb[256 * 32];     // weight plane; wave w owns rows w*64.. (16 KB)
  const int tid = threadIdx.x;
  const int w = tid >> 6, lane = tid & 63;
  const int quad = lane >> 4, l16 = lane & 15;
  const long m0 = (long)blockIdx.x * 64;
  const int srow = lane >> 2;
  const int scol = STAGE_COL(lane);

  // stage h tile once: 8 planes x 4 row-groups = 32 insts, 8 per wave
#pragma unroll
  for (int t = 0; t < 8; t++) {
    int p = 2 * w + t / 4, ii = t % 4;
    load_lds16(&H[(m0 + ii * 16 + srow) * 256 + p * 32 + scol], &As[(p * 2048) + (ii * 16) * 32]);
  }
  // prestage FFN1 macro-0 plane-0 weights (wave's own quarter)
#pragma unroll
  for (int ii = 0; ii < 4; ii++)
    load_lds16(&W1T[(long)(w * 64 + ii * 16 + srow) * 256 + scol], &Wb[(w * 64 + ii * 16) * 32]);
  __syncthreads();   // As (cross-wave) + own Wb plane 0 ready

  floatx4 acc2[4][4] = {};
  for (int m = 0; m < 4; m++) {          // ff1 macro of 256
    floatx4 acc1[4][4] = {};
    if (m > 0) {
#pragma unroll
      for (int ii = 0; ii < 4; ii++)
        load_lds16(&W1T[(long)(m * 256 + w * 64 + ii * 16 + srow) * 256 + scol],
                   &Wb[(w * 64 + ii * 16) * 32]);
    }
#pragma unroll 1
    for (int p = 0; p < 8; p++) {        // K(DIM) plane — per-wave fences, no barriers
      WAIT_VM0();                        // own staged plane landed
      shortx8 a[4], b[4];
#pragma unroll
      for (int i = 0; i < 4; i++)
        a[i] = *(const shortx8*)&Wb[FRAG_OFF(w * 64 + i * 16 + l16, quad)];
      WAIT_LGKM0();                      // frags in VGPRs; Wb quarter reusable
      if (p < 7) {
#pragma unroll
        for (int ii = 0; ii < 4; ii++)
          load_lds16(&W1T[(long)(m * 256 + w * 64 + ii * 16 + srow) * 256 + (p + 1) * 32 + scol],
                     &Wb[(w * 64 + ii * 16) * 32]);
      }
#pragma unroll
      for (int j = 0; j < 4; j++)
        b[j] = *(const shortx8*)&As[p * 2048 + FRAG_OFF(j * 16 + l16, quad)];
#pragma unroll
      for (int i = 0; i < 4; i++)
#pragma unroll
        for (int j = 0; j < 4; j++)
          acc1[i][j] = __builtin_amdgcn_mfma_f32_16x16x32_bf16(a[i], b[j], acc1[i][j], 0, 0, 0);
    }
    __syncthreads();   // all waves done reading Ss of macro m-1
    // relu + write S^T into Ss (A-layout, swizzled): 4 consecutive ff1 per store
#pragma unroll
    for (int i = 0; i < 4; i++) {
      int fb = w * 64 + i * 16 + quad * 4;   // ff1-in-macro base, 4 consecutive
      int pf = fb >> 5, c = (fb >> 3) & 3, off = fb & 7;
#pragma unroll
      for (int j = 0; j < 4; j++) {
        int tok = j * 16 + l16;
        ushort4 pk;
        pk.x = f2bf(fmaxf(acc1[i][j][0], 0.f));
        pk.y = f2bf(fmaxf(acc1[i][j][1], 0.f));
        pk.z = f2bf(fmaxf(acc1[i][j][2], 0.f));
        pk.w = f2bf(fmaxf(acc1[i][j][3], 0.f));
        *(ushort4*)&Ss[(pf * 64 + tok) * 32 + ((c ^ ((tok >> 1) & 3)) << 3) + off] = pk;
      }
    }
    __syncthreads();   // Ss visible to all waves
    // ---- FFN2 over this macro: A = S from LDS, B = W2 staged per-wave
#pragma unroll
    for (int jj = 0; jj < 4; jj++)
      load_lds16(&W2T[(long)(w * 64 + jj * 16 + srow) * 1024 + m * 256 + scol],
                 &Wb[(w * 64 + jj * 16) * 32]);
#pragma unroll 1
    for (int p = 0; p < 8; p++) {        // k-plane over ff1 macro — per-wave fences
      WAIT_VM0();
      shortx8 a[4], b[4];
#pragma unroll
      for (int j = 0; j < 4; j++)
        b[j] = *(const shortx8*)&Wb[FRAG_OFF(w * 64 + j * 16 + l16, quad)];
      WAIT_LGKM0();
      if (p < 7) {
#pragma unroll
        for (int jj = 0; jj < 4; jj++)
          load_lds16(&W2T[(long)(w * 64 + jj * 16 + srow) * 1024 + m * 256 + (p + 1) * 32 + scol],
                     &Wb[(w * 64 + jj * 16) * 32]);
      }
#pragma unroll
      for (int i = 0; i < 4; i++)
        a[i] = *(const shortx8*)&Ss[p * 2048 + FRAG_OFF(i * 16 + l16, quad)];
#pragma unroll
      for (int i = 0; i < 4; i++)
#pragma unroll
        for (int j = 0; j < 4; j++)
          acc2[i][j] = __builtin_amdgcn_mfma_f32_16x16x32_bf16(a[i], b[j], acc2[i][j], 0, 0, 0);
    }
  }
  __syncthreads();     // done reading Ss before red arrays alias it

  // epilogue: residual (H) + LN over full 256-col row; red arrays alias dead Ss
  float* red1 = (float*)Ss;
  float* red2 = red1 + 256;
  const int wc = w * 64;
#pragma unroll
  for (int i = 0; i < 4; i++)
#pragma unroll
    for (int r = 0; r < 4; r++) {
      int row = i * 16 + quad * 4 + r;   // 0..63
      float s1 = 0.f, s2 = 0.f;
#pragma unroll
      for (int j = 0; j < 4; j++) {
        float v = acc2[i][j][r] + bf2f(H[(m0 + row) * 256 + wc + j * 16 + l16]);
        acc2[i][j][r] = v;
        s1 += v;
        s2 += v * v;
      }
#pragma unroll
      for (int off = 1; off < 16; off <<= 1) {
        s1 += __shfl_xor(s1, off);
        s2 += __shfl_xor(s2, off);
      }
      if (l16 == 0) { red1[row * 4 + w] = s1; red2[row * 4 + w] = s2; }
    }
  __syncthreads();
#pragma unroll
  for (int i = 0; i < 4; i++)
#pragma unroll
    for (int r = 0; r < 4; r++) {
      int row = i * 16 + quad * 4 + r;
      float s1 = red1[row * 4] + red1[row * 4 + 1] + red1[row * 4 + 2] + red1[row * 4 + 3];
      float s2 = red2[row * 4] + red2[row * 4 + 1] + red2[row * 4 + 2] + red2[row * 4 + 3];
      float mean = s1 * (1.f / 256.f);
      float rstd = rsqrtf(s2 * (1.f / 256.f) - mean * mean + 1e-5f);
      if (m0 + row < M) {
#pragma unroll
        for (int j = 0; j < 4; j++)
          C[(m0 + row) * 256 + wc + j * 16 + l16] = f2bf((acc2[i][j][r] - mean) * rstd);
      }
    }
}

// ---------------- attention per sequence; o overwrites the q slot of qkv
template <int LSEQ, bool MASKED>
__global__ __launch_bounds__(256) void attn(const int* __restrict__ inputs,
                                            ushort* __restrict__ qkv) {
  __shared__ ushort Qs[LSEQ * 256];
  __shared__ ushort Ks[LSEQ * 256];
  __shared__ ushort Vs[LSEQ * 256];
  __shared__ float pads[LSEQ];
  const int blk = blockIdx.x;
  const int tid = threadIdx.x;
  ushort* base = qkv + (size_t)blk * LSEQ * 768;
  const uint4* src = (const uint4*)base;
  for (int i = tid; i < LSEQ * 96; i += 256) {
    int c = i / 96, part = i % 96;
    uint4 val = src[c * 96 + part];
    int sect = part >> 5, off = part & 31;
    ushort* dst = (sect == 0) ? Qs : (sect == 1 ? Ks : Vs);
    *(uint4*)&dst[c * 256 + off * 8] = val;
  }
  if (MASKED) {
    if (tid < LSEQ) pads[tid] = (inputs[blk * LSEQ + tid] == 0) ? 1.f : 0.f;
  }
  __syncthreads();
  if (tid < LSEQ * NHEAD) {
    const int i = tid % LSEQ, hh = tid / LSEQ;
    const int hb = hh * 32;
    float q[32];
    {
      const uint4* qr = (const uint4*)&Qs[i * 256 + hb];
#pragma unroll
      for (int u = 0; u < 4; u++) {
        uint4 ch = qr[u];
        const ushort* us = (const ushort*)&ch;
#pragma unroll
        for (int d = 0; d < 8; d++) q[u * 8 + d] = bf2f(us[d]);
      }
    }
    float s[LSEQ];
    float mx = -3e38f;
#pragma unroll
    for (int j = 0; j < LSEQ; j++) {
      const uint4* kr = (const uint4*)&Ks[j * 256 + hb];
      float a = 0.f;
#pragma unroll
      for (int u = 0; u < 4; u++) {
        uint4 ch = kr[u];
        const ushort* us = (const ushort*)&ch;
#pragma unroll
        for (int d = 0; d < 8; d++) a += q[u * 8 + d] * bf2f(us[d]);
      }
      a *= 0.17677669529663687f;
      if (MASKED && pads[j] != 0.f) a = -1e9f;
      s[j] = a;
      mx = fmaxf(mx, a);
    }
    float den = 0.f;
#pragma unroll
    for (int j = 0; j < LSEQ; j++) { s[j] = __expf(s[j] - mx); den += s[j]; }
    float inv = 1.f / den;
    float o[32] = {};
#pragma unroll
    for (int j = 0; j < LSEQ; j++) {
      float a = s[j] * inv;
      const uint4* vr = (const uint4*)&Vs[j * 256 + hb];
#pragma unroll
      for (int u = 0; u < 4; u++) {
        uint4 ch = vr[u];
        const ushort* us = (const ushort*)&ch;
#pragma unroll
        for (int d = 0; d < 8; d++) o[u * 8 + d] += a * bf2f(us[d]);
      }
    }
    ushort* orow = base + (size_t)i * 768 + hb;
#pragma unroll
    for (int d = 0; d < 32; d++) orow[d] = f2bf(o[d]);
  }
}

// ---------------- masked mean over chars -> scatter into padded + flag real slots
__global__ __launch_bounds__(256) void pool_scatter(const ushort* __restrict__ ft,
                                                    const int* __restrict__ inputs,
                                                    const int* __restrict__ cid,
                                                    const int* __restrict__ wpos,
                                                    ushort* __restrict__ padded,
                                                    int* __restrict__ flags) {
  int w = blockIdx.x, d = threadIdx.x;
  float s = 0.f;
  int cnt = 0;
  for (int c = 0; c < LW; c++) {
    if (inputs[w * LW + c] != 0) {
      s += bf2f(ft[((size_t)w * LW + c) * DIM + d]);
      cnt++;
    }
  }
  int slot = cid[w] * MAXW + wpos[w];
  padded[(size_t)slot * DIM + d] = f2bf(s / (float)cnt);
  if (d == 0) flags[slot] = 1;
}

// ---------------- final: mean over real word rows per concept -> f32 out
__global__ __launch_bounds__(256) void final_pool(const ushort* __restrict__ nft,
                                                  const int* __restrict__ flags,
                                                  float* __restrict__ out) {
  int n = blockIdx.x, d = threadIdx.x;
  float s = 0.f;
  int cnt = 0;
  for (int wd = 0; wd < MAXW; wd++) {
    if (flags[n * MAXW + wd]) {
      s += bf2f(nft[((size_t)n * MAXW + wd) * DIM + d]);
      cnt++;
    }
  }
  out[n * DIM + d] = s / (float)cnt;
}

extern "C" void kernel_launch(void* const* d_in, const int* in_sizes, int n_in,
                              void* d_out, int out_size, void* d_ws, size_t ws_size,
                              hipStream_t stream) {
  const int* inputs = (const int*)d_in[0];
  const int* cid = (const int*)d_in[1];
  const int* wpos = (const int*)d_in[2];
  const float* we_emb = (const float*)d_in[5];
  const float* we_qkv = (const float*)d_in[6];
  const float* we_o = (const float*)d_in[7];
  const float* we_ff1 = (const float*)d_in[8];
  const float* we_ff2 = (const float*)d_in[9];
  const float* ne_qkv = (const float*)d_in[10];
  const float* ne_o = (const float*)d_in[11];
  const float* ne_ff1 = (const float*)d_in[12];
  const float* ne_ff2 = (const float*)d_in[13];
  float* out = (float*)d_out;

  int chunks = 4;
  if (ws_size >= 515000000UL) chunks = 1;
  else if (ws_size >= 263258112UL) chunks = 2;
  const int wpc = NWORDS / chunks;
  const int tpc = wpc * LW;

  const size_t X = (size_t)tpc * DIM * 2;      // x / h size
  const size_t Q = (size_t)tpc * 768 * 2;      // qkv size

  char* base = (char*)d_ws;
  ushort* x = (ushort*)(base);
  ushort* qkv = (ushort*)(base + X);
  ushort* h = (ushort*)(base + X + Q);
  ushort* ft = qkv;                             // qkv dead after o-proj
  size_t pend = X + Q + X;
  ushort* padded = (ushort*)(base + pend);                // 8,388,608 B
  int* flags = (int*)(base + pend + 8388608);             // 65,536 B
  ushort* wT = (ushort*)(base + pend + 8454144);          // 3,145,728 B
  // name-stage buffers alias the word-stage region (dead by then)
  ushort* nqkv = (ushort*)(base);                         // 25,165,824
  ushort* nh = (ushort*)(base + 25165824);                // 8,388,608
  ushort* nft = (ushort*)(base + 33554432);               // 8,388,608

  ushort* wqkvT = wT;
  ushort* woT = wT + 196608;
  ushort* wff1T = wT + 262144;
  ushort* wff2T = wT + 524288;
  ushort* nqkvT = wT + 786432;
  ushort* neoT = wT + 983040;
  ushort* neff1T = wT + 1048576;
  ushort* neff2T = wT + 1310720;

  wprep<<<768, 256, 0, stream>>>(we_qkv, wqkvT, 256, 768);
  wprep<<<256, 256, 0, stream>>>(we_o, woT, 256, 256);
  wprep<<<1024, 256, 0, stream>>>(we_ff1, wff1T, 256, 1024);
  wprep<<<1024, 256, 0, stream>>>(we_ff2, wff2T, 1024, 256);
  wprep<<<768, 256, 0, stream>>>(ne_qkv, nqkvT, 256, 768);
  wprep<<<256, 256, 0, stream>>>(ne_o, neoT, 256, 256);
  wprep<<<1024, 256, 0, stream>>>(ne_ff1, neff1T, 256, 1024);
  wprep<<<1024, 256, 0, stream>>>(ne_ff2, neff2T, 1024, 256);

  (void)hipMemsetAsync(padded, 0, (size_t)TN * DIM * 2, stream);
  (void)hipMemsetAsync(flags, 0, TN * 4, stream);

  for (int c = 0; c < chunks; c++) {
    const int* in_c = inputs + (size_t)c * wpc * LW;
    const int* cid_c = cid + (size_t)c * wpc;
    const int* wpos_c = wpos + (size_t)c * wpc;

    embed4<<<tpc / 4, 256, 0, stream>>>(in_c, we_emb, x, tpc);
    // QKV: 3 N-tiles processed in-block (A staged once)
    {
      dim3 g(1, tpc / 64);
      gemm_tok64<false, 3><<<g, 256, 0, stream>>>(x, 256, wqkvT, nullptr, qkv, 768);
    }
    attn<24, true><<<wpc, 256, 0, stream>>>(in_c, qkv);
    // o-proj + residual(x) + LN -> h   (o lives in the q slot of qkv, lda=768)
    {
      dim3 g(1, tpc / 64);
      gemm_tok64<true, 1><<<g, 256, 0, stream>>>(qkv, 768, woT, x, h, 256);
    }
    ffn_fused<<<tpc / 64, 256, 0, stream>>>(h, wff1T, wff2T, ft, tpc);
    pool_scatter<<<wpc, 256, 0, stream>>>(ft, in_c, cid_c, wpos_c, padded, flags);
  }

  // name-level block
  {
    dim3 g(1, TN / 64);
    gemm_tok64<false, 3><<<g, 256, 0, stream>>>(padded, 256, nqkvT, nullptr, nqkv, 768);
  }
  attn<16, false><<<NCONC, 256, 0, stream>>>(nullptr, nqkv);
  {
    dim3 g(1, TN / 64);
    gemm_tok64<true, 1><<<g, 256, 0, stream>>>(nqkv, 768, neoT, padded, nh, 256);
  }
  ffn_fused<<<TN / 64, 256, 0, stream>>>(nh, neff1T, neff2T, nft, TN);
  final_pool<<<NCONC, 256, 0, stream>>>(nft, flags, out);
}

// Round 18
// 966.087 us; speedup vs baseline: 1.0131x; 1.0131x over previous
//
#include <hip/hip_runtime.h>
#include <hip/hip_bf16.h>

#define NWORDS 8192
#define LW 24
#define DIM 256
#define NHEAD 8
#define DFF 1024
#define NCONC 1024
#define MAXW 16
#define TN (NCONC * MAXW)          // 16384 name tokens

typedef float floatx4 __attribute__((ext_vector_type(4)));
typedef short shortx8 __attribute__((ext_vector_type(8)));

__device__ __forceinline__ float bf2f(ushort u) {
  union { uint u; float f; } v; v.u = ((uint)u) << 16; return v.f;
}
__device__ __forceinline__ ushort f2bf(float f) {
  union { float f; uint u; } v; v.f = f;
  return (ushort)((v.u + 0x7FFFu + ((v.u >> 16) & 1u)) >> 16);
}

// async global->LDS, 16B per lane; LDS dst is wave-uniform base + lane*16
__device__ __forceinline__ void load_lds16(const ushort* gsrc, ushort* lds) {
  __builtin_amdgcn_global_load_lds((const __attribute__((address_space(1))) void*)gsrc,
                                   (__attribute__((address_space(3))) void*)lds, 16, 0, 0);
}

// s_waitcnt imm: vmcnt[3:0]=b3:0,[5:4]=b15:14; expcnt=b6:4; lgkmcnt=b11:8
#define WAIT_VM0() __builtin_amdgcn_s_waitcnt(0x0F70)    // vmcnt(0), others max
#define WAIT_LGKM0() __builtin_amdgcn_s_waitcnt(0xC07F)  // lgkmcnt(0), others max

// Swizzled LDS tile (R6-verified: SQ_LDS_BANK_CONFLICT == 0): rows of 32 ushort
// (64B) in 4 16B chunks; chunk c of row r stored at slot c ^ ((r>>1)&3).
#define STAGE_COL(lane) ((((lane) & 3) ^ (((lane) >> 3) & 3)) * 8)
#define FRAG_OFF(row, quad) (((row) * 32) + ((((quad) ^ (((row) >> 1) & 3))) * 8))

// ---------------- weight transpose + cast: W[K x N] f32 -> WT[N x K] bf16
__global__ __launch_bounds__(256) void wprep(const float* __restrict__ W,
                                             ushort* __restrict__ WT, int K, int N) {
  int idx = blockIdx.x * 256 + threadIdx.x;
  if (idx < K * N) {
    int k = idx / N, n = idx % N;
    WT[n * K + k] = f2bf(W[idx]);
  }
}

// ---------------- embedding gather -> bf16 x (vectorized: 1 thread = 4 elems)
__global__ __launch_bounds__(256) void embed4(const int* __restrict__ inputs,
                                              const float* __restrict__ we_emb,
                                              ushort* __restrict__ x, int ntok) {
  int idx = blockIdx.x * 256 + threadIdx.x;
  int t = idx >> 6, d = (idx & 63) * 4;
  if (t < ntok) {
    const float4 f = *(const float4*)&we_emb[inputs[t] * DIM + d];
    uint2 o;
    o.x = (uint)f2bf(f.x) | ((uint)f2bf(f.y) << 16);
    o.y = (uint)f2bf(f.z) | ((uint)f2bf(f.w) << 16);
    *(uint2*)&x[(size_t)t * DIM + d] = o;
  }
}

// ---------------- GEMM, K=256 fixed, 64 tokens/block, N-tile 256 per block
// (blockIdx.x selects the N-tile; wave owns 64 cols).  v6-proven structure:
// A-tile (32 KB) staged ONCE; weights per-wave staged with s_waitcnt fences ->
// barrier-free K-loop.  Optional residual+LN (requires gridDim.x==1).
template <bool LN>
__global__ __launch_bounds__(256, 2) void gemm_tok64(const ushort* __restrict__ A, int lda,
                                                     const ushort* __restrict__ BT,  // [N x 256]
                                                     const ushort* __restrict__ RES, // [M x 256] | null
                                                     ushort* __restrict__ C, int ldc) {
  __shared__ __align__(16) ushort As[8 * 64 * 32];  // tokens: 8 k-planes x 64 rows (32 KB)
  __shared__ __align__(16) ushort Wb[256 * 32];     // weight plane; wave w owns rows w*64.. (16 KB)
  __shared__ float red1[64 * 4];
  __shared__ float red2[64 * 4];
  const int tid = threadIdx.x;
  const int w = tid >> 6, lane = tid & 63;
  const int quad = lane >> 4, l16 = lane & 15;
  const long m0 = (long)blockIdx.y * 64;
  const long nb = (long)blockIdx.x * 256;           // N-tile base
  const int srow = lane >> 2;
  const int scol = STAGE_COL(lane);
  const int wc = w * 64;

  // stage A tile once: 8 planes x 4 row-groups = 32 insts, 8 per wave
#pragma unroll
  for (int t = 0; t < 8; t++) {
    int p = 2 * w + t / 4, ii = t % 4;
    load_lds16(&A[(m0 + ii * 16 + srow) * lda + p * 32 + scol], &As[p * 2048 + (ii * 16) * 32]);
  }
  // prestage weight plane 0 (wave's own quarter)
#pragma unroll
  for (int ii = 0; ii < 4; ii++)
    load_lds16(&BT[(nb + wc + ii * 16 + srow) * 256 + scol], &Wb[(wc + ii * 16) * 32]);
  __syncthreads();   // As (cross-wave) + own Wb plane 0 ready

  floatx4 acc[4][4] = {};
#pragma unroll 1
  for (int p = 0; p < 8; p++) {        // K plane — per-wave fences, no barriers
    WAIT_VM0();                        // own staged plane landed
    shortx8 a[4], b[4];
#pragma unroll
    for (int j = 0; j < 4; j++)
      b[j] = *(const shortx8*)&Wb[FRAG_OFF(wc + j * 16 + l16, quad)];
    WAIT_LGKM0();                      // frags in VGPRs; Wb quarter reusable
    if (p < 7) {
#pragma unroll
      for (int ii = 0; ii < 4; ii++)
        load_lds16(&BT[(nb + wc + ii * 16 + srow) * 256 + (p + 1) * 32 + scol],
                   &Wb[(wc + ii * 16) * 32]);
    }
#pragma unroll
    for (int i = 0; i < 4; i++)
      a[i] = *(const shortx8*)&As[p * 2048 + FRAG_OFF(i * 16 + l16, quad)];
#pragma unroll
    for (int i = 0; i < 4; i++)
#pragma unroll
      for (int j = 0; j < 4; j++)
        acc[i][j] = __builtin_amdgcn_mfma_f32_16x16x32_bf16(a[i], b[j], acc[i][j], 0, 0, 0);
  }

  if (!LN) {
    // plain store (used for QKV; C is the 768-wide qkv buffer)
#pragma unroll
    for (int i = 0; i < 4; i++)
#pragma unroll
      for (int j = 0; j < 4; j++)
#pragma unroll
        for (int r = 0; r < 4; r++) {
          long m = m0 + i * 16 + quad * 4 + r;
          C[m * ldc + nb + wc + j * 16 + l16] = f2bf(acc[i][j][r]);
        }
    return;
  }

  // residual + LN epilogue (N==256, gridDim.x==1 -> nb==0)
#pragma unroll
  for (int i = 0; i < 4; i++)
#pragma unroll
    for (int r = 0; r < 4; r++) {
      int row = i * 16 + quad * 4 + r;
      float s1 = 0.f, s2 = 0.f;
#pragma unroll
      for (int j = 0; j < 4; j++) {
        float v = acc[i][j][r] + bf2f(RES[(m0 + row) * 256 + wc + j * 16 + l16]);
        acc[i][j][r] = v;
        s1 += v;
        s2 += v * v;
      }
#pragma unroll
      for (int off = 1; off < 16; off <<= 1) {
        s1 += __shfl_xor(s1, off);
        s2 += __shfl_xor(s2, off);
      }
      if (l16 == 0) { red1[row * 4 + w] = s1; red2[row * 4 + w] = s2; }
    }
  __syncthreads();
#pragma unroll
  for (int i = 0; i < 4; i++)
#pragma unroll
    for (int r = 0; r < 4; r++) {
      int row = i * 16 + quad * 4 + r;
      float s1 = red1[row * 4] + red1[row * 4 + 1] + red1[row * 4 + 2] + red1[row * 4 + 3];
      float s2 = red2[row * 4] + red2[row * 4 + 1] + red2[row * 4 + 2] + red2[row * 4 + 3];
      float mean = s1 * (1.f / 256.f);
      float rstd = rsqrtf(s2 * (1.f / 256.f) - mean * mean + 1e-5f);
#pragma unroll
      for (int j = 0; j < 4; j++)
        C[(m0 + row) * 256 + wc + j * 16 + l16] = f2bf((acc[i][j][r] - mean) * rstd);
    }
}

// ---------------- fused FFN: C = LN(h + relu(h W1) W2), 64 rows/block, 4 waves.
// (R12/R14 winner)
__global__ __launch_bounds__(256, 2) void ffn_fused(const ushort* __restrict__ H,   // [M x 256]
                                                    const ushort* __restrict__ W1T, // [1024 x 256]
                                                    const ushort* __restrict__ W2T, // [256 x 1024]
                                                    ushort* __restrict__ C,         // [M x 256]
                                                    int M) {
  __shared__ __align__(16) ushort As[8 * 64 * 32];  // h: 8 k-planes x 64 rows (32 KB)
  __shared__ __align__(16) ushort Ss[8 * 64 * 32];  // S macro: 8 planes x 64 rows (32 KB)
  __shared__ __align__(16) ushort Wb[256 * 32];     // weight plane; wave w owns rows w*64.. (16 KB)
  const int tid = threadIdx.x;
  const int w = tid >> 6, lane = tid & 63;
  const int quad = lane >> 4, l16 = lane & 15;
  const long m0 = (long)blockIdx.x * 64;
  const int srow = lane >> 2;
  const int scol = STAGE_COL(lane);

  // stage h tile once: 8 planes x 4 row-groups = 32 insts, 8 per wave
#pragma unroll
  for (int t = 0; t < 8; t++) {
    int p = 2 * w + t / 4, ii = t % 4;
    load_lds16(&H[(m0 + ii * 16 + srow) * 256 + p * 32 + scol], &As[(p * 2048) + (ii * 16) * 32]);
  }
  // prestage FFN1 macro-0 plane-0 weights (wave's own quarter)
#pragma unroll
  for (int ii = 0; ii < 4; ii++)
    load_lds16(&W1T[(long)(w * 64 + ii * 16 + srow) * 256 + scol], &Wb[(w * 64 + ii * 16) * 32]);
  __syncthreads();   // As (cross-wave) + own Wb plane 0 ready

  floatx4 acc2[4][4] = {};
  for (int m = 0; m < 4; m++) {          // ff1 macro of 256
    floatx4 acc1[4][4] = {};
    if (m > 0) {
#pragma unroll
      for (int ii = 0; ii < 4; ii++)
        load_lds16(&W1T[(long)(m * 256 + w * 64 + ii * 16 + srow) * 256 + scol],
                   &Wb[(w * 64 + ii * 16) * 32]);
    }
#pragma unroll 1
    for (int p = 0; p < 8; p++) {        // K(DIM) plane — per-wave fences, no barriers
      WAIT_VM0();                        // own staged plane landed
      shortx8 a[4], b[4];
#pragma unroll
      for (int i = 0; i < 4; i++)
        a[i] = *(const shortx8*)&Wb[FRAG_OFF(w * 64 + i * 16 + l16, quad)];
      WAIT_LGKM0();                      // frags in VGPRs; Wb quarter reusable
      if (p < 7) {
#pragma unroll
        for (int ii = 0; ii < 4; ii++)
          load_lds16(&W1T[(long)(m * 256 + w * 64 + ii * 16 + srow) * 256 + (p + 1) * 32 + scol],
                     &Wb[(w * 64 + ii * 16) * 32]);
      }
#pragma unroll
      for (int j = 0; j < 4; j++)
        b[j] = *(const shortx8*)&As[p * 2048 + FRAG_OFF(j * 16 + l16, quad)];
#pragma unroll
      for (int i = 0; i < 4; i++)
#pragma unroll
        for (int j = 0; j < 4; j++)
          acc1[i][j] = __builtin_amdgcn_mfma_f32_16x16x32_bf16(a[i], b[j], acc1[i][j], 0, 0, 0);
    }
    __syncthreads();   // all waves done reading Ss of macro m-1
    // relu + write S^T into Ss (A-layout, swizzled): 4 consecutive ff1 per store
#pragma unroll
    for (int i = 0; i < 4; i++) {
      int fb = w * 64 + i * 16 + quad * 4;   // ff1-in-macro base, 4 consecutive
      int pf = fb >> 5, c = (fb >> 3) & 3, off = fb & 7;
#pragma unroll
      for (int j = 0; j < 4; j++) {
        int tok = j * 16 + l16;
        ushort4 pk;
        pk.x = f2bf(fmaxf(acc1[i][j][0], 0.f));
        pk.y = f2bf(fmaxf(acc1[i][j][1], 0.f));
        pk.z = f2bf(fmaxf(acc1[i][j][2], 0.f));
        pk.w = f2bf(fmaxf(acc1[i][j][3], 0.f));
        *(ushort4*)&Ss[(pf * 64 + tok) * 32 + ((c ^ ((tok >> 1) & 3)) << 3) + off] = pk;
      }
    }
    __syncthreads();   // Ss visible to all waves
    // ---- FFN2 over this macro: A = S from LDS, B = W2 staged per-wave
#pragma unroll
    for (int jj = 0; jj < 4; jj++)
      load_lds16(&W2T[(long)(w * 64 + jj * 16 + srow) * 1024 + m * 256 + scol],
                 &Wb[(w * 64 + jj * 16) * 32]);
#pragma unroll 1
    for (int p = 0; p < 8; p++) {        // k-plane over ff1 macro — per-wave fences
      WAIT_VM0();
      shortx8 a[4], b[4];
#pragma unroll
      for (int j = 0; j < 4; j++)
        b[j] = *(const shortx8*)&Wb[FRAG_OFF(w * 64 + j * 16 + l16, quad)];
      WAIT_LGKM0();
      if (p < 7) {
#pragma unroll
        for (int jj = 0; jj < 4; jj++)
          load_lds16(&W2T[(long)(w * 64 + jj * 16 + srow) * 1024 + m * 256 + (p + 1) * 32 + scol],
                     &Wb[(w * 64 + jj * 16) * 32]);
      }
#pragma unroll
      for (int i = 0; i < 4; i++)
        a[i] = *(const shortx8*)&Ss[p * 2048 + FRAG_OFF(i * 16 + l16, quad)];
#pragma unroll
      for (int i = 0; i < 4; i++)
#pragma unroll
        for (int j = 0; j < 4; j++)
          acc2[i][j] = __builtin_amdgcn_mfma_f32_16x16x32_bf16(a[i], b[j], acc2[i][j], 0, 0, 0);
    }
  }
  __syncthreads();     // done reading Ss before red arrays alias it

  // epilogue: residual (H) + LN over full 256-col row; red arrays alias dead Ss
  float* red1 = (float*)Ss;
  float* red2 = red1 + 256;
  const int wc = w * 64;
#pragma unroll
  for (int i = 0; i < 4; i++)
#pragma unroll
    for (int r = 0; r < 4; r++) {
      int row = i * 16 + quad * 4 + r;   // 0..63
      float s1 = 0.f, s2 = 0.f;
#pragma unroll
      for (int j = 0; j < 4; j++) {
        float v = acc2[i][j][r] + bf2f(H[(m0 + row) * 256 + wc + j * 16 + l16]);
        acc2[i][j][r] = v;
        s1 += v;
        s2 += v * v;
      }
#pragma unroll
      for (int off = 1; off < 16; off <<= 1) {
        s1 += __shfl_xor(s1, off);
        s2 += __shfl_xor(s2, off);
      }
      if (l16 == 0) { red1[row * 4 + w] = s1; red2[row * 4 + w] = s2; }
    }
  __syncthreads();
#pragma unroll
  for (int i = 0; i < 4; i++)
#pragma unroll
    for (int r = 0; r < 4; r++) {
      int row = i * 16 + quad * 4 + r;
      float s1 = red1[row * 4] + red1[row * 4 + 1] + red1[row * 4 + 2] + red1[row * 4 + 3];
      float s2 = red2[row * 4] + red2[row * 4 + 1] + red2[row * 4 + 2] + red2[row * 4 + 3];
      float mean = s1 * (1.f / 256.f);
      float rstd = rsqrtf(s2 * (1.f / 256.f) - mean * mean + 1e-5f);
      if (m0 + row < M) {
#pragma unroll
        for (int j = 0; j < 4; j++)
          C[(m0 + row) * 256 + wc + j * 16 + l16] = f2bf((acc2[i][j][r] - mean) * rstd);
      }
    }
}

// ---------------- attention per sequence; o overwrites the q slot of qkv
template <int LSEQ, bool MASKED>
__global__ __launch_bounds__(256) void attn(const int* __restrict__ inputs,
                                            ushort* __restrict__ qkv) {
  __shared__ ushort Qs[LSEQ * 256];
  __shared__ ushort Ks[LSEQ * 256];
  __shared__ ushort Vs[LSEQ * 256];
  __shared__ float pads[LSEQ];
  const int blk = blockIdx.x;
  const int tid = threadIdx.x;
  ushort* base = qkv + (size_t)blk * LSEQ * 768;
  const uint4* src = (const uint4*)base;
  for (int i = tid; i < LSEQ * 96; i += 256) {
    int c = i / 96, part = i % 96;
    uint4 val = src[c * 96 + part];
    int sect = part >> 5, off = part & 31;
    ushort* dst = (sect == 0) ? Qs : (sect == 1 ? Ks : Vs);
    *(uint4*)&dst[c * 256 + off * 8] = val;
  }
  if (MASKED) {
    if (tid < LSEQ) pads[tid] = (inputs[blk * LSEQ + tid] == 0) ? 1.f : 0.f;
  }
  __syncthreads();
  if (tid < LSEQ * NHEAD) {
    const int i = tid % LSEQ, hh = tid / LSEQ;
    const int hb = hh * 32;
    float q[32];
    {
      const uint4* qr = (const uint4*)&Qs[i * 256 + hb];
#pragma unroll
      for (int u = 0; u < 4; u++) {
        uint4 ch = qr[u];
        const ushort* us = (const ushort*)&ch;
#pragma unroll
        for (int d = 0; d < 8; d++) q[u * 8 + d] = bf2f(us[d]);
      }
    }
    float s[LSEQ];
    float mx = -3e38f;
#pragma unroll
    for (int j = 0; j < LSEQ; j++) {
      const uint4* kr = (const uint4*)&Ks[j * 256 + hb];
      float a = 0.f;
#pragma unroll
      for (int u = 0; u < 4; u++) {
        uint4 ch = kr[u];
        const ushort* us = (const ushort*)&ch;
#pragma unroll
        for (int d = 0; d < 8; d++) a += q[u * 8 + d] * bf2f(us[d]);
      }
      a *= 0.17677669529663687f;
      if (MASKED && pads[j] != 0.f) a = -1e9f;
      s[j] = a;
      mx = fmaxf(mx, a);
    }
    float den = 0.f;
#pragma unroll
    for (int j = 0; j < LSEQ; j++) { s[j] = __expf(s[j] - mx); den += s[j]; }
    float inv = 1.f / den;
    float o[32] = {};
#pragma unroll
    for (int j = 0; j < LSEQ; j++) {
      float a = s[j] * inv;
      const uint4* vr = (const uint4*)&Vs[j * 256 + hb];
#pragma unroll
      for (int u = 0; u < 4; u++) {
        uint4 ch = vr[u];
        const ushort* us = (const ushort*)&ch;
#pragma unroll
        for (int d = 0; d < 8; d++) o[u * 8 + d] += a * bf2f(us[d]);
      }
    }
    ushort* orow = base + (size_t)i * 768 + hb;
#pragma unroll
    for (int d = 0; d < 32; d++) orow[d] = f2bf(o[d]);
  }
}

// ---------------- masked mean over chars -> scatter into padded + flag real slots
__global__ __launch_bounds__(256) void pool_scatter(const ushort* __restrict__ ft,
                                                    const int* __restrict__ inputs,
                                                    const int* __restrict__ cid,
                                                    const int* __restrict__ wpos,
                                                    ushort* __restrict__ padded,
                                                    int* __restrict__ flags) {
  int w = blockIdx.x, d = threadIdx.x;
  float s = 0.f;
  int cnt = 0;
  for (int c = 0; c < LW; c++) {
    if (inputs[w * LW + c] != 0) {
      s += bf2f(ft[((size_t)w * LW + c) * DIM + d]);
      cnt++;
    }
  }
  int slot = cid[w] * MAXW + wpos[w];
  padded[(size_t)slot * DIM + d] = f2bf(s / (float)cnt);
  if (d == 0) flags[slot] = 1;
}

// ---------------- final: mean over real word rows per concept -> f32 out
__global__ __launch_bounds__(256) void final_pool(const ushort* __restrict__ nft,
                                                  const int* __restrict__ flags,
                                                  float* __restrict__ out) {
  int n = blockIdx.x, d = threadIdx.x;
  float s = 0.f;
  int cnt = 0;
  for (int wd = 0; wd < MAXW; wd++) {
    if (flags[n * MAXW + wd]) {
      s += bf2f(nft[((size_t)n * MAXW + wd) * DIM + d]);
      cnt++;
    }
  }
  out[n * DIM + d] = s / (float)cnt;
}

extern "C" void kernel_launch(void* const* d_in, const int* in_sizes, int n_in,
                              void* d_out, int out_size, void* d_ws, size_t ws_size,
                              hipStream_t stream) {
  const int* inputs = (const int*)d_in[0];
  const int* cid = (const int*)d_in[1];
  const int* wpos = (const int*)d_in[2];
  const float* we_emb = (const float*)d_in[5];
  const float* we_qkv = (const float*)d_in[6];
  const float* we_o = (const float*)d_in[7];
  const float* we_ff1 = (const float*)d_in[8];
  const float* we_ff2 = (const float*)d_in[9];
  const float* ne_qkv = (const float*)d_in[10];
  const float* ne_o = (const float*)d_in[11];
  const float* ne_ff1 = (const float*)d_in[12];
  const float* ne_ff2 = (const float*)d_in[13];
  float* out = (float*)d_out;

  int chunks = 4;
  if (ws_size >= 515000000UL) chunks = 1;
  else if (ws_size >= 263258112UL) chunks = 2;
  const int wpc = NWORDS / chunks;
  const int tpc = wpc * LW;

  const size_t X = (size_t)tpc * DIM * 2;      // x / h size
  const size_t Q = (size_t)tpc * 768 * 2;      // qkv size

  char* base = (char*)d_ws;
  ushort* x = (ushort*)(base);
  ushort* qkv = (ushort*)(base + X);
  ushort* h = (ushort*)(base + X + Q);
  ushort* ft = qkv;                             // qkv dead after o-proj
  size_t pend = X + Q + X;
  ushort* padded = (ushort*)(base + pend);                // 8,388,608 B
  int* flags = (int*)(base + pend + 8388608);             // 65,536 B
  ushort* wT = (ushort*)(base + pend + 8454144);          // 3,145,728 B
  // name-stage buffers alias the word-stage region (dead by then)
  ushort* nqkv = (ushort*)(base);                         // 25,165,824
  ushort* nh = (ushort*)(base + 25165824);                // 8,388,608
  ushort* nft = (ushort*)(base + 33554432);               // 8,388,608

  ushort* wqkvT = wT;
  ushort* woT = wT + 196608;
  ushort* wff1T = wT + 262144;
  ushort* wff2T = wT + 524288;
  ushort* nqkvT = wT + 786432;
  ushort* neoT = wT + 983040;
  ushort* neff1T = wT + 1048576;
  ushort* neff2T = wT + 1310720;

  wprep<<<768, 256, 0, stream>>>(we_qkv, wqkvT, 256, 768);
  wprep<<<256, 256, 0, stream>>>(we_o, woT, 256, 256);
  wprep<<<1024, 256, 0, stream>>>(we_ff1, wff1T, 256, 1024);
  wprep<<<1024, 256, 0, stream>>>(we_ff2, wff2T, 1024, 256);
  wprep<<<768, 256, 0, stream>>>(ne_qkv, nqkvT, 256, 768);
  wprep<<<256, 256, 0, stream>>>(ne_o, neoT, 256, 256);
  wprep<<<1024, 256, 0, stream>>>(ne_ff1, neff1T, 256, 1024);
  wprep<<<1024, 256, 0, stream>>>(ne_ff2, neff2T, 1024, 256);

  (void)hipMemsetAsync(padded, 0, (size_t)TN * DIM * 2, stream);
  (void)hipMemsetAsync(flags, 0, TN * 4, stream);

  for (int c = 0; c < chunks; c++) {
    const int* in_c = inputs + (size_t)c * wpc * LW;
    const int* cid_c = cid + (size_t)c * wpc;
    const int* wpos_c = wpos + (size_t)c * wpc;

    embed4<<<tpc / 4, 256, 0, stream>>>(in_c, we_emb, x, tpc);
    // QKV: 3 N-tiles of 256 over the 768-wide output (blockIdx.x = N-tile)
    {
      dim3 g(3, tpc / 64);
      gemm_tok64<false><<<g, 256, 0, stream>>>(x, 256, wqkvT, nullptr, qkv, 768);
    }
    attn<24, true><<<wpc, 256, 0, stream>>>(in_c, qkv);
    // o-proj + residual(x) + LN -> h   (o lives in the q slot of qkv, lda=768)
    {
      dim3 g(1, tpc / 64);
      gemm_tok64<true><<<g, 256, 0, stream>>>(qkv, 768, woT, x, h, 256);
    }
    ffn_fused<<<tpc / 64, 256, 0, stream>>>(h, wff1T, wff2T, ft, tpc);
    pool_scatter<<<wpc, 256, 0, stream>>>(ft, in_c, cid_c, wpos_c, padded, flags);
  }

  // name-level block
  {
    dim3 g(3, TN / 64);
    gemm_tok64<false><<<g, 256, 0, stream>>>(padded, 256, nqkvT, nullptr, nqkv, 768);
  }
  attn<16, false><<<NCONC, 256, 0, stream>>>(nullptr, nqkv);
  {
    dim3 g(1, TN / 64);
    gemm_tok64<true><<<g, 256, 0, stream>>>(nqkv, 768, neoT, padded, nh, 256);
  }
  ffn_fused<<<TN / 64, 256, 0, stream>>>(nh, neff1T, neff2T, nft, TN);
  final_pool<<<NCONC, 256, 0, stream>>>(nft, flags, out);
}